// Round 9
// baseline (194.366 us; speedup 1.0000x reference)
//
#include <hip/hip_runtime.h>
#include <hip/hip_bf16.h>
#include <stdint.h>

#define SEQ 2048
#define NBH 64            // B*H = 4*16
#define HD 64

typedef __bf16     bx8   __attribute__((ext_vector_type(8)));
typedef float      fx4   __attribute__((ext_vector_type(4)));
typedef float      f32x16 __attribute__((ext_vector_type(16)));
typedef uint32_t   ux2   __attribute__((ext_vector_type(2)));
typedef unsigned short us8 __attribute__((ext_vector_type(8)));

__device__ __forceinline__ float bf2f(unsigned short u){
  uint32_t x = ((uint32_t)u) << 16; return __builtin_bit_cast(float, x);
}
__device__ __forceinline__ unsigned short f2bf_rne(float f){
  uint32_t u = __builtin_bit_cast(uint32_t, f);
  return (unsigned short)((u + 0x7FFFu + ((u >> 16) & 1u)) >> 16);
}
__device__ __forceinline__ uint32_t cvtpk(float lo, float hi){
  uint32_t r; asm("v_cvt_pk_bf16_f32 %0, %1, %2" : "=v"(r) : "v"(lo), "v"(hi));
  return r;
}

typedef __attribute__((address_space(3))) void  lvoid;
typedef const __attribute__((address_space(1))) void gvoid;
__device__ __forceinline__ void gll16(const void* g, void* l){
  __builtin_amdgcn_global_load_lds((gvoid*)(uintptr_t)g,
                                   (lvoid*)(uint32_t)(uintptr_t)l, 16, 0, 0);
}

template<int OFF>
__device__ __forceinline__ ux2 tr16(uint32_t addr){
  ux2 d;
  asm volatile("ds_read_b64_tr_b16 %0, %1 offset:%2" : "=v"(d) : "v"(addr), "i"(OFF));
  return d;
}
__device__ __forceinline__ bx8 mk8(ux2 a, ux2 b){
  union { uint32_t u[4]; bx8 v; } U;
  U.u[0]=a[0]; U.u[1]=a[1]; U.u[2]=b[0]; U.u[3]=b[1];
  return U.v;
}
__device__ __forceinline__ bx8 mk8u(uint32_t u0, uint32_t u1, uint32_t u2, uint32_t u3){
  union { uint32_t u[4]; bx8 v; } U;
  U.u[0]=u0; U.u[1]=u1; U.u[2]=u2; U.u[3]=u3;
  return U.v;
}

// ---------------- cast f32 -> bf16 (RNE), 8 elems/thread ----------------
__global__ void castk(const float* __restrict__ in, unsigned short* __restrict__ out, int n){
  int i = (blockIdx.x * 256 + threadIdx.x) * 8;
  if (i + 7 < n){
    const float4* p = (const float4*)(in + i);
    float4 a = p[0], b = p[1];
    us8 r;
    r[0]=f2bf_rne(a.x); r[1]=f2bf_rne(a.y); r[2]=f2bf_rne(a.z); r[3]=f2bf_rne(a.w);
    r[4]=f2bf_rne(b.x); r[5]=f2bf_rne(b.y); r[6]=f2bf_rne(b.z); r[7]=f2bf_rne(b.w);
    *(us8*)(out + i) = r;
  }
}

// ---------------- 256x128 8-wave 4-phase-barriered GEMM: C = A * Bw^T ----------------
// 512 thr = 8 waves (4M x 2N), per-wave C = 64x64, BK=64, LDS 96 KiB (2 dbuf).
// Per K-tile: 4 phases {ds_read frags; issue 2 gll; bar; setprio 8xMFMA; bar};
// stage spread over ph0-ph2; vmcnt(0) only at ph3 (issued >=3 phases earlier).
// EPI 0: scatter Q/K/V bf16 [3][64][2048][64] + bias.  EPI 1: f32 [M,N] + bias.
template<int EPI>
__global__ __launch_bounds__(512, 2) void gemm256(
    const unsigned short* __restrict__ A, const unsigned short* __restrict__ Bw,
    const float* __restrict__ bias, void* __restrict__ outp, int N, int K)
{
  __shared__ __align__(16) unsigned short Al[2][256*64];
  __shared__ __align__(16) unsigned short Bl[2][128*64];
  const int tid = threadIdx.x;
  const int w = tid >> 6, l = tid & 63;
  const int l15 = l & 15, lg = l >> 4;
  const int wr = w >> 1, wc = w & 1;
  // bijective XCD chunk swizzle (nwg % 8 == 0 for both grids)
  const int flat = blockIdx.y * gridDim.x + blockIdx.x;
  const int cpx = (gridDim.x * gridDim.y) >> 3;
  const int nid = (flat & 7) * cpx + (flat >> 3);
  const int bx = nid % gridDim.x, by = nid / gridDim.x;
  const int brow = by * 256, bcol = bx * 128;

  fx4 acc[4][4];   // [m-tile 0..3 within wave's 64 rows][n-tile]
  #pragma unroll
  for (int m = 0; m < 4; m++)
    #pragma unroll
    for (int n = 0; n < 4; n++) acc[m][n] = (fx4){0.f,0.f,0.f,0.f};

  auto stageA = [&](int buf, int k0, int part){   // 2 gll, rows part*128..part*128+127
    #pragma unroll
    for (int i = 0; i < 2; i++){
      int g = (part*2 + i)*512 + tid;
      int row = g >> 3, c = (g & 7) ^ (row & 7);
      gll16(A + (size_t)(brow + row) * K + k0 + c*8, &Al[buf][g*8]);
    }
  };
  auto stageB = [&](int buf, int k0){             // 2 gll, full 128-row B tile
    #pragma unroll
    for (int i = 0; i < 2; i++){
      int g = i*512 + tid;
      int row = g >> 3, c = (g & 7) ^ (row & 7);
      gll16(Bw + (size_t)(bcol + row) * K + k0 + c*8, &Bl[buf][g*8]);
    }
  };

  // prologue: tile 0 fully staged
  stageA(0, 0, 0); stageA(0, 0, 1); stageB(0, 0);
  asm volatile("s_waitcnt vmcnt(0)" ::: "memory");
  __builtin_amdgcn_s_barrier();

  int cur = 0;
  for (int k0 = 0; k0 < K; k0 += 64){
    const bool pre = (k0 + 64 < K);
    const int nk = k0 + 64;
    bx8 bfr[4], afr[2];

    // ---- ph0: B(kc0) + A(m01,kc0) ∥ stageA p0 ----
    #pragma unroll
    for (int n = 0; n < 4; n++){
      int row = wc*64 + n*16 + l15;
      bfr[n] = *(const bx8*)&Bl[cur][row*64 + (lg ^ (row & 7))*8];
    }
    #pragma unroll
    for (int m = 0; m < 2; m++){
      int row = wr*64 + m*16 + l15;
      afr[m] = *(const bx8*)&Al[cur][row*64 + (lg ^ (row & 7))*8];
    }
    if (pre) stageA(cur ^ 1, nk, 0);
    __builtin_amdgcn_s_barrier();
    __builtin_amdgcn_s_setprio(1);
    #pragma unroll
    for (int m = 0; m < 2; m++)
      #pragma unroll
      for (int n = 0; n < 4; n++)
        acc[m][n] = __builtin_amdgcn_mfma_f32_16x16x32_bf16(afr[m], bfr[n], acc[m][n], 0, 0, 0);
    __builtin_amdgcn_s_setprio(0);
    __builtin_amdgcn_s_barrier();

    // ---- ph1: A(m23,kc0) ∥ stageA p1 ----
    #pragma unroll
    for (int m = 0; m < 2; m++){
      int row = wr*64 + (m + 2)*16 + l15;
      afr[m] = *(const bx8*)&Al[cur][row*64 + (lg ^ (row & 7))*8];
    }
    if (pre) stageA(cur ^ 1, nk, 1);
    __builtin_amdgcn_s_barrier();
    __builtin_amdgcn_s_setprio(1);
    #pragma unroll
    for (int m = 0; m < 2; m++)
      #pragma unroll
      for (int n = 0; n < 4; n++)
        acc[m + 2][n] = __builtin_amdgcn_mfma_f32_16x16x32_bf16(afr[m], bfr[n], acc[m + 2][n], 0, 0, 0);
    __builtin_amdgcn_s_setprio(0);
    __builtin_amdgcn_s_barrier();

    // ---- ph2: B(kc1) + A(m01,kc1) ∥ stageB ----
    #pragma unroll
    for (int n = 0; n < 4; n++){
      int row = wc*64 + n*16 + l15;
      bfr[n] = *(const bx8*)&Bl[cur][row*64 + ((4 + lg) ^ (row & 7))*8];
    }
    #pragma unroll
    for (int m = 0; m < 2; m++){
      int row = wr*64 + m*16 + l15;
      afr[m] = *(const bx8*)&Al[cur][row*64 + ((4 + lg) ^ (row & 7))*8];
    }
    if (pre) stageB(cur ^ 1, nk);
    __builtin_amdgcn_s_barrier();
    __builtin_amdgcn_s_setprio(1);
    #pragma unroll
    for (int m = 0; m < 2; m++)
      #pragma unroll
      for (int n = 0; n < 4; n++)
        acc[m][n] = __builtin_amdgcn_mfma_f32_16x16x32_bf16(afr[m], bfr[n], acc[m][n], 0, 0, 0);
    __builtin_amdgcn_s_setprio(0);
    __builtin_amdgcn_s_barrier();

    // ---- ph3: A(m23,kc1); tile-boundary wait ----
    #pragma unroll
    for (int m = 0; m < 2; m++){
      int row = wr*64 + (m + 2)*16 + l15;
      afr[m] = *(const bx8*)&Al[cur][row*64 + ((4 + lg) ^ (row & 7))*8];
    }
    __builtin_amdgcn_s_barrier();
    __builtin_amdgcn_s_setprio(1);
    #pragma unroll
    for (int m = 0; m < 2; m++)
      #pragma unroll
      for (int n = 0; n < 4; n++)
        acc[m + 2][n] = __builtin_amdgcn_mfma_f32_16x16x32_bf16(afr[m], bfr[n], acc[m + 2][n], 0, 0, 0);
    __builtin_amdgcn_s_setprio(0);
    asm volatile("s_waitcnt vmcnt(0)" ::: "memory");  // next tile's 6 loads (issued >=3 phases ago)
    __builtin_amdgcn_s_barrier();                      // WAR: all reads of cur done; RAW: nxt visible
    cur ^= 1;
  }

  // ---- epilogue ----
  #pragma unroll
  for (int m = 0; m < 4; m++){
    int row0 = brow + wr*64 + m*16 + lg*4;
    #pragma unroll
    for (int n = 0; n < 4; n++){
      int col = bcol + wc*64 + n*16 + l15;
      float bq = bias[col];
      if (EPI == 0){
        int which = col >> 10, rem = col & 1023, h = rem >> 6, d = rem & 63;
        #pragma unroll
        for (int i = 0; i < 4; i++){
          int r = row0 + i; int b = r >> 11, s = r & 2047;
          size_t idx = (((size_t)which*64 + (size_t)b*16 + h) * 2048 + s) * 64 + d;
          ((unsigned short*)outp)[idx] = f2bf_rne(acc[m][n][i] + bq);
        }
      } else {
        #pragma unroll
        for (int i = 0; i < 4; i++){
          int r = row0 + i;
          ((float*)outp)[(size_t)r * N + col] = acc[m][n][i] + bq;
        }
      }
    }
  }
}

// ---------------- flash attention, swapped-QK^T 32x32, static-m softmax ----------------
// (unchanged from R6)
__global__ __launch_bounds__(256, 4) void attn_k(const unsigned short* __restrict__ qkv,
                                                 unsigned short* __restrict__ ob)
{
  __shared__ __align__(16) unsigned short Kl[2][64*64];   // [kv][64d], XOR-swizzled chunks
  __shared__ __align__(16) unsigned short Vl[2][64*64];   // subtiled [n=4][kv=64][16d]
  __shared__ float lsc[4][32];
  const int tid = threadIdx.x, w = tid >> 6, l = tid & 63;
  const int l31 = l & 31, hi = l >> 5, l15 = l & 15;
  const int flat = blockIdx.y * 16 + blockIdx.x;
  const int nid  = (flat & 7) * 128 + (flat >> 3);
  const int qblk = nid & 15, bh = nid >> 4;
  const unsigned short* Qh = qkv + (size_t)bh * SEQ * HD;
  const unsigned short* Kh = qkv + (size_t)(NBH + bh) * SEQ * HD;
  const unsigned short* Vh = qkv + (size_t)(2*NBH + bh) * SEQ * HD;
  const int q0 = qblk * 128;

  const int g0 = tid, g1 = 256 + tid;
  const int kr0 = g0 >> 3, kc0 = ((g0 & 7) ^ (kr0 & 7));
  const int kr1 = g1 >> 3, kc1 = ((g1 & 7) ^ (kr1 & 7));
  const int kb0 = kr0*64 + kc0*8, kb1 = kr1*64 + kc1*8;
  const int e0 = g0*8, e1 = g1*8;
  const int vb0 = ((e0 >> 4) & 63)*64 + (e0 >> 10)*16 + (e0 & 15);
  const int vb1 = ((e1 >> 4) & 63)*64 + (e1 >> 10)*16 + (e1 & 15);

  unsigned short* KlF = &Kl[0][0];
  #pragma unroll
  for (int i = 0; i < 4; i++){
    int g = i*256 + tid; int row = g >> 3; int c = (g & 7) ^ (row & 7);
    gll16(Qh + (size_t)(q0 + row) * 64 + c*8, &KlF[g*8]);
  }
  asm volatile("s_waitcnt vmcnt(0)" ::: "memory");
  __syncthreads();
  bx8 qf[4];
  {
    int qrow = w*32 + l31;
    #pragma unroll
    for (int dk = 0; dk < 4; dk++){
      int ch = (dk*2 + hi) ^ (qrow & 7);
      qf[dk] = *(const bx8*)&KlF[qrow*64 + ch*8];
    }
  }
  __syncthreads();

  auto stage = [&](int buf, int t){
    const unsigned short* kp = Kh + t*4096;
    const unsigned short* vp = Vh + t*4096;
    gll16(kp + kb0, &Kl[buf][g0*8]);
    gll16(kp + kb1, &Kl[buf][g1*8]);
    gll16(vp + vb0, &Vl[buf][e0]);
    gll16(vp + vb1, &Vl[buf][e1]);
  };

  const float SCL = 0.125f * 1.44269504f;
  const float MB  = 24.0f;
  float lsum = 0.f;
  f32x16 acco[2] = {};

  stage(0, 0);
  int cur = 0;
  const uint32_t vlane = (uint32_t)((l31 >> 4)*2048 + hi*256 + l15*8);

  for (int t = 0; t < SEQ/64; t++){
    if (t + 1 < SEQ/64){
      stage(cur ^ 1, t + 1);
      asm volatile("s_waitcnt vmcnt(4)" ::: "memory");
    } else {
      asm volatile("s_waitcnt vmcnt(0)" ::: "memory");
    }
    __builtin_amdgcn_s_barrier();

    const uint32_t vbb = (uint32_t)(uintptr_t)&Vl[cur][0];
    bx8 pa[4];

    f32x16 sb0 = {}, sb1 = {};
    __builtin_amdgcn_s_setprio(1);
    #pragma unroll
    for (int dk = 0; dk < 4; dk++){
      int ch = (dk*2 + hi) ^ (l31 & 7);
      bx8 a0 = *(const bx8*)&Kl[cur][l31*64 + ch*8];
      sb0 = __builtin_amdgcn_mfma_f32_32x32x16_bf16(a0, qf[dk], sb0, 0, 0, 0);
    }
    #pragma unroll
    for (int dk = 0; dk < 4; dk++){
      int ch = (dk*2 + hi) ^ (l31 & 7);
      bx8 a1 = *(const bx8*)&Kl[cur][(32 + l31)*64 + ch*8];
      sb1 = __builtin_amdgcn_mfma_f32_32x32x16_bf16(a1, qf[dk], sb1, 0, 0, 0);
    }
    __builtin_amdgcn_s_setprio(0);

    #pragma unroll
    for (int r = 0; r < 16; r++){
      float p = __builtin_amdgcn_exp2f(__builtin_fmaf(sb0[r], SCL, -MB));
      sb0[r] = p; lsum += p;
    }
    #pragma unroll
    for (int hf = 0; hf < 2; hf++){
      const int r0 = hf * 8;
      uint32_t c01 = cvtpk(sb0[r0+0], sb0[r0+1]);
      uint32_t c23 = cvtpk(sb0[r0+2], sb0[r0+3]);
      uint32_t c45 = cvtpk(sb0[r0+4], sb0[r0+5]);
      uint32_t c67 = cvtpk(sb0[r0+6], sb0[r0+7]);
      asm("v_permlane32_swap_b32 %0, %1" : "+v"(c01), "+v"(c45));
      asm("v_permlane32_swap_b32 %0, %1" : "+v"(c23), "+v"(c67));
      pa[hf] = mk8u(c01, c23, c45, c67);
    }

    ux2 vrA[2][2][2];
    #pragma unroll
    for (int kvs = 0; kvs < 2; kvs++)
      #pragma unroll
      for (int db = 0; db < 2; db++){
        uint32_t a = vbb + vlane + db*4096 + kvs*512;
        vrA[kvs][db][0] = tr16<0>(a);
        vrA[kvs][db][1] = tr16<128>(a);
      }

    #pragma unroll
    for (int r = 0; r < 16; r++){
      float p = __builtin_amdgcn_exp2f(__builtin_fmaf(sb1[r], SCL, -MB));
      sb1[r] = p; lsum += p;
    }
    #pragma unroll
    for (int hf = 0; hf < 2; hf++){
      const int r0 = hf * 8;
      uint32_t c01 = cvtpk(sb1[r0+0], sb1[r0+1]);
      uint32_t c23 = cvtpk(sb1[r0+2], sb1[r0+3]);
      uint32_t c45 = cvtpk(sb1[r0+4], sb1[r0+5]);
      uint32_t c67 = cvtpk(sb1[r0+6], sb1[r0+7]);
      asm("v_permlane32_swap_b32 %0, %1" : "+v"(c01), "+v"(c45));
      asm("v_permlane32_swap_b32 %0, %1" : "+v"(c23), "+v"(c67));
      pa[2 + hf] = mk8u(c01, c23, c45, c67);
    }

    ux2 vrB[2][2][2];
    #pragma unroll
    for (int kvs = 0; kvs < 2; kvs++)
      #pragma unroll
      for (int db = 0; db < 2; db++){
        uint32_t a = vbb + vlane + db*4096 + (kvs + 2)*512;
        vrB[kvs][db][0] = tr16<0>(a);
        vrB[kvs][db][1] = tr16<128>(a);
      }

    asm volatile("s_waitcnt lgkmcnt(8)" ::: "memory");
    __builtin_amdgcn_sched_barrier(0);
    __builtin_amdgcn_s_setprio(1);
    #pragma unroll
    for (int kvs = 0; kvs < 2; kvs++)
      #pragma unroll
      for (int db = 0; db < 2; db++)
        acco[db] = __builtin_amdgcn_mfma_f32_32x32x16_bf16(
            pa[kvs], mk8(vrA[kvs][db][0], vrA[kvs][db][1]), acco[db], 0, 0, 0);
    __builtin_amdgcn_s_setprio(0);
    asm volatile("s_waitcnt lgkmcnt(0)" ::: "memory");
    __builtin_amdgcn_sched_barrier(0);
    __builtin_amdgcn_s_setprio(1);
    #pragma unroll
    for (int kvs = 0; kvs < 2; kvs++)
      #pragma unroll
      for (int db = 0; db < 2; db++)
        acco[db] = __builtin_amdgcn_mfma_f32_32x32x16_bf16(
            pa[2 + kvs], mk8(vrB[kvs][db][0], vrB[kvs][db][1]), acco[db], 0, 0, 0);
    __builtin_amdgcn_s_setprio(0);
    __builtin_amdgcn_s_barrier();
    cur ^= 1;
  }

  float lsf = lsum + __shfl_xor(lsum, 32);
  lsc[w][l31] = lsf;
  float inv[16];
  #pragma unroll
  for (int r = 0; r < 16; r++){
    int q = (r & 3) + 8*(r >> 2) + 4*hi;
    inv[r] = 1.0f / lsc[w][q];
  }
  const int b = bh >> 4, h = bh & 15;
  #pragma unroll
  for (int r = 0; r < 16; r++){
    int qg = q0 + w*32 + (r & 3) + 8*(r >> 2) + 4*hi;
    size_t base = ((size_t)b * 2048 + qg) * 1024 + h*64;
    ob[base + l31]      = f2bf_rne(acco[0][r] * inv[r]);
    ob[base + 32 + l31] = f2bf_rne(acco[1][r] * inv[r]);
  }
}

extern "C" void kernel_launch(void* const* d_in, const int* in_sizes, int n_in,
                              void* d_out, int out_size, void* d_ws, size_t ws_size,
                              hipStream_t stream) {
  const float* x     = (const float*)d_in[0];
  const float* wqkv  = (const float*)d_in[1];
  const float* bqkv  = (const float*)d_in[2];
  const float* wproj = (const float*)d_in[3];
  const float* bproj = (const float*)d_in[4];
  float* out = (float*)d_out;

  char* ws = (char*)d_ws;
  unsigned short* xb     = (unsigned short*)(ws);              // 16.78 MB
  unsigned short* obuf   = (unsigned short*)(ws + 16777216);   // 16.78 MB
  unsigned short* wqkvb  = (unsigned short*)(ws + 33554432);   // 6.29 MB
  unsigned short* wprojb = (unsigned short*)(ws + 39845888);   // 2.10 MB
  unsigned short* qkvb   = (unsigned short*)(ws + 41943040);   // 50.33 MB

  castk<<<dim3(4096), dim3(256), 0, stream>>>(x,     xb,     8388608);
  castk<<<dim3(1536), dim3(256), 0, stream>>>(wqkv,  wqkvb,  3145728);
  castk<<<dim3(512),  dim3(256), 0, stream>>>(wproj, wprojb, 1048576);

  gemm256<0><<<dim3(24, 32), dim3(512), 0, stream>>>(xb, wqkvb, bqkv, (void*)qkvb, 3072, 1024);
  attn_k    <<<dim3(16, 64), dim3(256), 0, stream>>>(qkvb, obuf);
  gemm256<1><<<dim3(8, 32),  dim3(512), 0, stream>>>(obuf, wprojb, bproj, (void*)out, 1024, 1024);
}

// Round 10
// 180.297 us; speedup vs baseline: 1.0780x; 1.0780x over previous
//
#include <hip/hip_runtime.h>
#include <hip/hip_bf16.h>
#include <stdint.h>

#define SEQ 2048
#define NBH 64            // B*H = 4*16
#define HD 64

typedef __bf16     bx8   __attribute__((ext_vector_type(8)));
typedef float      fx4   __attribute__((ext_vector_type(4)));
typedef float      f32x16 __attribute__((ext_vector_type(16)));
typedef uint32_t   ux2   __attribute__((ext_vector_type(2)));
typedef unsigned short us8 __attribute__((ext_vector_type(8)));

__device__ __forceinline__ float bf2f(unsigned short u){
  uint32_t x = ((uint32_t)u) << 16; return __builtin_bit_cast(float, x);
}
__device__ __forceinline__ unsigned short f2bf_rne(float f){
  uint32_t u = __builtin_bit_cast(uint32_t, f);
  return (unsigned short)((u + 0x7FFFu + ((u >> 16) & 1u)) >> 16);
}
__device__ __forceinline__ uint32_t cvtpk(float lo, float hi){
  uint32_t r; asm("v_cvt_pk_bf16_f32 %0, %1, %2" : "=v"(r) : "v"(lo), "v"(hi));
  return r;
}

typedef __attribute__((address_space(3))) void  lvoid;
typedef const __attribute__((address_space(1))) void gvoid;
__device__ __forceinline__ void gll16(const void* g, void* l){
  __builtin_amdgcn_global_load_lds((gvoid*)(uintptr_t)g,
                                   (lvoid*)(uint32_t)(uintptr_t)l, 16, 0, 0);
}

template<int OFF>
__device__ __forceinline__ ux2 tr16(uint32_t addr){
  ux2 d;
  asm volatile("ds_read_b64_tr_b16 %0, %1 offset:%2" : "=v"(d) : "v"(addr), "i"(OFF));
  return d;
}
__device__ __forceinline__ bx8 mk8(ux2 a, ux2 b){
  union { uint32_t u[4]; bx8 v; } U;
  U.u[0]=a[0]; U.u[1]=a[1]; U.u[2]=b[0]; U.u[3]=b[1];
  return U.v;
}
__device__ __forceinline__ bx8 mk8u(uint32_t u0, uint32_t u1, uint32_t u2, uint32_t u3){
  union { uint32_t u[4]; bx8 v; } U;
  U.u[0]=u0; U.u[1]=u1; U.u[2]=u2; U.u[3]=u3;
  return U.v;
}

// ---------------- cast f32 -> bf16 (RNE), 8 elems/thread ----------------
__global__ void castk(const float* __restrict__ in, unsigned short* __restrict__ out, int n){
  int i = (blockIdx.x * 256 + threadIdx.x) * 8;
  if (i + 7 < n){
    const float4* p = (const float4*)(in + i);
    float4 a = p[0], b = p[1];
    us8 r;
    r[0]=f2bf_rne(a.x); r[1]=f2bf_rne(a.y); r[2]=f2bf_rne(a.z); r[3]=f2bf_rne(a.w);
    r[4]=f2bf_rne(b.x); r[5]=f2bf_rne(b.y); r[6]=f2bf_rne(b.z); r[7]=f2bf_rne(b.w);
    *(us8*)(out + i) = r;
  }
}

// ---------------- GEMM: C[M,N] = A[M,K] * Bw[N,K]^T  (bf16 in, f32 acc) ----------------
// R7 version (best measured): counted-vmcnt 2-phase, 128x128 tile.
template<int EPI>
__global__ __launch_bounds__(256, 2) void gemm_bt(
    const unsigned short* __restrict__ A, const unsigned short* __restrict__ Bw,
    const float* __restrict__ bias, void* __restrict__ outp,
    int M, int N, int K)
{
  __shared__ __align__(16) unsigned short Al[2][128*64];
  __shared__ __align__(16) unsigned short Bl[2][128*64];
  const int tid = threadIdx.x;
  const int w = tid >> 6, l = tid & 63;
  const int l15 = l & 15, lg = l >> 4;
  const int wr = w >> 1, wc = w & 1;
  const int brow = blockIdx.y * 128, bcol = blockIdx.x * 128;

  fx4 acc[4][4];
  #pragma unroll
  for (int m = 0; m < 4; m++)
    #pragma unroll
    for (int n = 0; n < 4; n++) acc[m][n] = (fx4){0.f,0.f,0.f,0.f};

  auto stage = [&](int buf, int k0){
    #pragma unroll
    for (int i = 0; i < 4; i++){
      int g = i*256 + tid; int row = g >> 3; int c = (g & 7) ^ (row & 7);
      gll16(A + (size_t)(brow + row) * K + k0 + c*8, &Al[buf][g*8]);
    }
    #pragma unroll
    for (int i = 0; i < 4; i++){
      int g = i*256 + tid; int row = g >> 3; int c = (g & 7) ^ (row & 7);
      gll16(Bw + (size_t)(bcol + row) * K + k0 + c*8, &Bl[buf][g*8]);
    }
  };

  stage(0, 0);
  int cur = 0;
  for (int k0 = 0; k0 < K; k0 += 64){
    if (k0 + 64 < K){
      stage(cur ^ 1, k0 + 64);
      asm volatile("s_waitcnt vmcnt(8)" ::: "memory");
    } else {
      asm volatile("s_waitcnt vmcnt(0)" ::: "memory");
    }
    __builtin_amdgcn_s_barrier();

    bx8 af[4][2], bf[4][2];
    #pragma unroll
    for (int kc = 0; kc < 2; kc++){
      #pragma unroll
      for (int m = 0; m < 4; m++){
        int row = wr*64 + m*16 + l15;
        int ch  = (kc*4 + lg) ^ (row & 7);
        af[m][kc] = *(const bx8*)&Al[cur][row*64 + ch*8];
      }
      #pragma unroll
      for (int n = 0; n < 4; n++){
        int row = wc*64 + n*16 + l15;
        int ch  = (kc*4 + lg) ^ (row & 7);
        bf[n][kc] = *(const bx8*)&Bl[cur][row*64 + ch*8];
      }
    }
    #pragma unroll
    for (int kc = 0; kc < 2; kc++)
      #pragma unroll
      for (int m = 0; m < 4; m++)
        #pragma unroll
        for (int n = 0; n < 4; n++)
          acc[m][n] = __builtin_amdgcn_mfma_f32_16x16x32_bf16(af[m][kc], bf[n][kc], acc[m][n], 0, 0, 0);
    __builtin_amdgcn_s_barrier();
    cur ^= 1;
  }

  #pragma unroll
  for (int m = 0; m < 4; m++){
    int row0 = brow + wr*64 + m*16 + lg*4;
    #pragma unroll
    for (int n = 0; n < 4; n++){
      int col = bcol + wc*64 + n*16 + l15;
      float bq = bias[col];
      if (EPI == 0){
        int which = col >> 10, rem = col & 1023, h = rem >> 6, d = rem & 63;
        #pragma unroll
        for (int i = 0; i < 4; i++){
          int r = row0 + i; int b = r >> 11, s = r & 2047;
          size_t idx = (((size_t)which*64 + (size_t)b*16 + h) * 2048 + s) * 64 + d;
          ((unsigned short*)outp)[idx] = f2bf_rne(acc[m][n][i] + bq);
        }
      } else {
        #pragma unroll
        for (int i = 0; i < 4; i++){
          int r = row0 + i;
          ((float*)outp)[(size_t)r * N + col] = acc[m][n][i] + bq;
        }
      }
    }
  }
}

// ---------------- flash attention, swapped-QK^T 32x32, static-m softmax ----------------
// R10: QBLK=256/block, 8 waves (512 thr), grid 512 = exactly 2 blocks/CU ->
// single dispatch round, zero tail; K/V staging per q-row halved; Q frags read
// directly from global (no LDS prologue). Per-wave math identical to R6.
__global__ __launch_bounds__(512, 2) void attn_k(const unsigned short* __restrict__ qkv,
                                                 unsigned short* __restrict__ ob)
{
  __shared__ __align__(16) unsigned short Kl[2][64*64];   // [kv][64d], XOR-swizzled chunks
  __shared__ __align__(16) unsigned short Vl[2][64*64];   // subtiled [n=4][kv=64][16d]
  __shared__ float lsc[8][32];
  const int tid = threadIdx.x, w = tid >> 6, l = tid & 63;
  const int l31 = l & 31, hi = l >> 5, l15 = l & 15;
  // XCD-chunked remap over 512 blocks: each XCD gets 64 consecutive nids
  // = 8 heads' full work -> per-XCD KV working set 8*512KB = 4MB = one L2.
  const int flat = blockIdx.y * 8 + blockIdx.x;
  const int nid  = (flat & 7) * 64 + (flat >> 3);
  const int qblk = nid & 7, bh = nid >> 3;
  const unsigned short* Qh = qkv + (size_t)bh * SEQ * HD;
  const unsigned short* Kh = qkv + (size_t)(NBH + bh) * SEQ * HD;
  const unsigned short* Vh = qkv + (size_t)(2*NBH + bh) * SEQ * HD;
  const int q0 = qblk * 256;

  // per-thread invariant staging offsets (512 threads stage one 64x64 K + V tile)
  const int kr0 = tid >> 3, kc0 = ((tid & 7) ^ (kr0 & 7));
  const int kb0 = kr0*64 + kc0*8;
  const int e0 = tid*8;
  const int vb0 = ((e0 >> 4) & 63)*64 + (e0 >> 10)*16 + (e0 & 15);

  // ---- Q fragments direct from global: qf[dk][j] = Q[qrow][dk*16+hi*8+j] ----
  bx8 qf[4];
  {
    int qrow = q0 + w*32 + l31;
    const unsigned short* qp = Qh + (size_t)qrow * 64 + hi*8;
    #pragma unroll
    for (int dk = 0; dk < 4; dk++)
      qf[dk] = *(const bx8*)(qp + dk*16);
  }

  auto stage = [&](int buf, int t){   // 2 vmem instructions per thread
    const unsigned short* kp = Kh + t*4096;
    const unsigned short* vp = Vh + t*4096;
    gll16(kp + kb0, &Kl[buf][tid*8]);
    gll16(vp + vb0, &Vl[buf][e0]);
  };

  const float SCL = 0.125f * 1.44269504f;   // log2e / 8 (attn scale folded in)
  const float MB  = 24.0f;                  // static log2-domain max bound
  float lsum = 0.f;
  f32x16 acco[2] = {};

  stage(0, 0);
  int cur = 0;
  const uint32_t vlane = (uint32_t)((l31 >> 4)*2048 + hi*256 + l15*8);

  for (int t = 0; t < SEQ/64; t++){
    if (t + 1 < SEQ/64){
      stage(cur ^ 1, t + 1);
      asm volatile("s_waitcnt vmcnt(2)" ::: "memory");
    } else {
      asm volatile("s_waitcnt vmcnt(0)" ::: "memory");
    }
    __builtin_amdgcn_s_barrier();

    const uint32_t vbb = (uint32_t)(uintptr_t)&Vl[cur][0];
    bx8 pa[4];

    // ---- QK^T: sb0 chain (kv 0-31), then sb1 (kv 32-63) ----
    f32x16 sb0 = {}, sb1 = {};
    __builtin_amdgcn_s_setprio(1);
    #pragma unroll
    for (int dk = 0; dk < 4; dk++){
      int ch = (dk*2 + hi) ^ (l31 & 7);
      bx8 a0 = *(const bx8*)&Kl[cur][l31*64 + ch*8];
      sb0 = __builtin_amdgcn_mfma_f32_32x32x16_bf16(a0, qf[dk], sb0, 0, 0, 0);
    }
    #pragma unroll
    for (int dk = 0; dk < 4; dk++){
      int ch = (dk*2 + hi) ^ (l31 & 7);
      bx8 a1 = *(const bx8*)&Kl[cur][(32 + l31)*64 + ch*8];
      sb1 = __builtin_amdgcn_mfma_f32_32x32x16_bf16(a1, qf[dk], sb1, 0, 0, 0);
    }
    __builtin_amdgcn_s_setprio(0);

    // ---- softmax + pack sb0 (overlaps sb1 MFMA tail) ----
    #pragma unroll
    for (int r = 0; r < 16; r++){
      float p = __builtin_amdgcn_exp2f(__builtin_fmaf(sb0[r], SCL, -MB));
      sb0[r] = p; lsum += p;
    }
    #pragma unroll
    for (int hf = 0; hf < 2; hf++){
      const int r0 = hf * 8;
      uint32_t c01 = cvtpk(sb0[r0+0], sb0[r0+1]);
      uint32_t c23 = cvtpk(sb0[r0+2], sb0[r0+3]);
      uint32_t c45 = cvtpk(sb0[r0+4], sb0[r0+5]);
      uint32_t c67 = cvtpk(sb0[r0+6], sb0[r0+7]);
      asm("v_permlane32_swap_b32 %0, %1" : "+v"(c01), "+v"(c45));
      asm("v_permlane32_swap_b32 %0, %1" : "+v"(c23), "+v"(c67));
      pa[hf] = mk8u(c01, c23, c45, c67);
    }

    // ---- V tr-reads group A (kvs 0,1) ----
    ux2 vrA[2][2][2];
    #pragma unroll
    for (int kvs = 0; kvs < 2; kvs++)
      #pragma unroll
      for (int db = 0; db < 2; db++){
        uint32_t a = vbb + vlane + db*4096 + kvs*512;
        vrA[kvs][db][0] = tr16<0>(a);
        vrA[kvs][db][1] = tr16<128>(a);
      }

    // ---- softmax + pack sb1 ----
    #pragma unroll
    for (int r = 0; r < 16; r++){
      float p = __builtin_amdgcn_exp2f(__builtin_fmaf(sb1[r], SCL, -MB));
      sb1[r] = p; lsum += p;
    }
    #pragma unroll
    for (int hf = 0; hf < 2; hf++){
      const int r0 = hf * 8;
      uint32_t c01 = cvtpk(sb1[r0+0], sb1[r0+1]);
      uint32_t c23 = cvtpk(sb1[r0+2], sb1[r0+3]);
      uint32_t c45 = cvtpk(sb1[r0+4], sb1[r0+5]);
      uint32_t c67 = cvtpk(sb1[r0+6], sb1[r0+7]);
      asm("v_permlane32_swap_b32 %0, %1" : "+v"(c01), "+v"(c45));
      asm("v_permlane32_swap_b32 %0, %1" : "+v"(c23), "+v"(c67));
      pa[2 + hf] = mk8u(c01, c23, c45, c67);
    }

    // ---- V tr-reads group B (kvs 2,3) ----
    ux2 vrB[2][2][2];
    #pragma unroll
    for (int kvs = 0; kvs < 2; kvs++)
      #pragma unroll
      for (int db = 0; db < 2; db++){
        uint32_t a = vbb + vlane + db*4096 + (kvs + 2)*512;
        vrB[kvs][db][0] = tr16<0>(a);
        vrB[kvs][db][1] = tr16<128>(a);
      }

    // ---- O += P*V : group A ----
    asm volatile("s_waitcnt lgkmcnt(8)" ::: "memory");
    __builtin_amdgcn_sched_barrier(0);
    __builtin_amdgcn_s_setprio(1);
    #pragma unroll
    for (int kvs = 0; kvs < 2; kvs++)
      #pragma unroll
      for (int db = 0; db < 2; db++)
        acco[db] = __builtin_amdgcn_mfma_f32_32x32x16_bf16(
            pa[kvs], mk8(vrA[kvs][db][0], vrA[kvs][db][1]), acco[db], 0, 0, 0);
    __builtin_amdgcn_s_setprio(0);
    // ---- group B ----
    asm volatile("s_waitcnt lgkmcnt(0)" ::: "memory");
    __builtin_amdgcn_sched_barrier(0);
    __builtin_amdgcn_s_setprio(1);
    #pragma unroll
    for (int kvs = 0; kvs < 2; kvs++)
      #pragma unroll
      for (int db = 0; db < 2; db++)
        acco[db] = __builtin_amdgcn_mfma_f32_32x32x16_bf16(
            pa[2 + kvs], mk8(vrB[kvs][db][0], vrB[kvs][db][1]), acco[db], 0, 0, 0);
    __builtin_amdgcn_s_setprio(0);
    __builtin_amdgcn_s_barrier();
    cur ^= 1;
  }

  // ---- epilogue: merge pair sums, divide, store ----
  float lsf = lsum + __shfl_xor(lsum, 32);
  lsc[w][l31] = lsf;
  float inv[16];
  #pragma unroll
  for (int r = 0; r < 16; r++){
    int q = (r & 3) + 8*(r >> 2) + 4*hi;
    inv[r] = 1.0f / lsc[w][q];
  }
  const int b = bh >> 4, h = bh & 15;
  #pragma unroll
  for (int r = 0; r < 16; r++){
    int qg = q0 + w*32 + (r & 3) + 8*(r >> 2) + 4*hi;
    size_t base = ((size_t)b * 2048 + qg) * 1024 + h*64;
    ob[base + l31]      = f2bf_rne(acco[0][r] * inv[r]);
    ob[base + 32 + l31] = f2bf_rne(acco[1][r] * inv[r]);
  }
}

extern "C" void kernel_launch(void* const* d_in, const int* in_sizes, int n_in,
                              void* d_out, int out_size, void* d_ws, size_t ws_size,
                              hipStream_t stream) {
  const float* x     = (const float*)d_in[0];
  const float* wqkv  = (const float*)d_in[1];
  const float* bqkv  = (const float*)d_in[2];
  const float* wproj = (const float*)d_in[3];
  const float* bproj = (const float*)d_in[4];
  float* out = (float*)d_out;

  char* ws = (char*)d_ws;
  unsigned short* xb     = (unsigned short*)(ws);              // 16.78 MB
  unsigned short* obuf   = (unsigned short*)(ws + 16777216);   // 16.78 MB
  unsigned short* wqkvb  = (unsigned short*)(ws + 33554432);   // 6.29 MB
  unsigned short* wprojb = (unsigned short*)(ws + 39845888);   // 2.10 MB
  unsigned short* qkvb   = (unsigned short*)(ws + 41943040);   // 50.33 MB

  castk<<<dim3(4096), dim3(256), 0, stream>>>(x,     xb,     8388608);
  castk<<<dim3(1536), dim3(256), 0, stream>>>(wqkv,  wqkvb,  3145728);
  castk<<<dim3(512),  dim3(256), 0, stream>>>(wproj, wprojb, 1048576);

  gemm_bt<0><<<dim3(24, 64), dim3(256), 0, stream>>>(xb, wqkvb, bqkv, (void*)qkvb, 8192, 3072, 1024);
  attn_k    <<<dim3(8, 64),  dim3(512), 0, stream>>>(qkvb, obuf);
  gemm_bt<1><<<dim3(8, 64),  dim3(256), 0, stream>>>(obuf, wprojb, bproj, (void*)out, 8192, 1024, 1024);
}